// Round 10
// baseline (98.233 us; speedup 1.0000x reference)
//
#include <hip/hip_runtime.h>

typedef unsigned short u16;
typedef unsigned int   u32;
typedef __attribute__((ext_vector_type(8))) short bf16x8;
typedef __attribute__((ext_vector_type(4))) float f32x4;

#define LROW 4096
#define NB   8192
#define PCOL 720
#define NPAD 768
#define HH   2048
#define INV_SQRT2F 0.70710678118654752440f

// ws layout: xbf | G | std
#define WS_XBF_BYTES ((size_t)67108864)           // 8192*4096*2
#define WS_G_BYTES   ((size_t)6291456)            // 768*4096*2
#define WS_MIN       (WS_XBF_BYTES + WS_G_BYTES + (size_t)NB * 4)

__device__ __forceinline__ u16 f2bf(float f) {
    union { float f; u32 u; } v; v.f = f;
    u32 r = v.u + 0x7FFFu + ((v.u >> 16) & 1u);
    return (u16)(r >> 16);
}

#define SWZ(i) ((i) ^ (((i) >> 5) & 31))

// ---------------------------------------------------------------------------
// Kernel P: per-row moving-average (via prefix sum), std (ddof=1), x -> bf16
// ---------------------------------------------------------------------------
__global__ __launch_bounds__(256) void prep_rows(const float* __restrict__ x,
                                                 u16* __restrict__ xbf,
                                                 float* __restrict__ stdv) {
    __shared__ float S[LROW];
    __shared__ float wred[4];
    __shared__ float ends[2];
    __shared__ float rred[8];
    const int tid = threadIdx.x;
    const int lane = tid & 63, wv = tid >> 6;
    const size_t b = blockIdx.x;

    const float4* xr4 = (const float4*)(x + b * LROW);
    float4 q0 = xr4[tid * 4 + 0], q1 = xr4[tid * 4 + 1];
    float4 q2 = xr4[tid * 4 + 2], q3 = xr4[tid * 4 + 3];
    float r[16];
    r[0]=q0.x; r[1]=q0.y; r[2]=q0.z; r[3]=q0.w;
    r[4]=q1.x; r[5]=q1.y; r[6]=q1.z; r[7]=q1.w;
    r[8]=q2.x; r[9]=q2.y; r[10]=q2.z; r[11]=q2.w;
    r[12]=q3.x; r[13]=q3.y; r[14]=q3.z; r[15]=q3.w;

    float ps[16];
    float a = 0.f;
    #pragma unroll
    for (int k = 0; k < 16; ++k) { a += r[k]; ps[k] = a; }
    const float segsum = a;

    float v = segsum;
    #pragma unroll
    for (int off = 1; off < 64; off <<= 1) {
        float o = __shfl_up(v, off);
        if (lane >= off) v += o;
    }
    if (lane == 63) wred[wv] = v;
    if (tid == 0)   ends[0] = r[0];
    if (tid == 255) ends[1] = r[15];
    __syncthreads();

    float wbase = 0.f;
    #pragma unroll
    for (int w = 0; w < 4; ++w) if (w < wv) wbase += wred[w];
    const float ebase = wbase + v - segsum;

    #pragma unroll
    for (int k = 0; k < 16; ++k) {
        const int i = (tid << 4) + k;
        S[SWZ(i)] = ebase + ps[k];
    }
    __syncthreads();

    const float x0 = ends[0], xl = ends[1];
    float s1 = 0.f, s2 = 0.f;
    u16 ob[16];
    #pragma unroll
    for (int k = 0; k < 16; ++k) {
        const int i = (tid << 4) + k;
        int h = i + 12; h = h > LROW - 1 ? LROW - 1 : h;
        float wsum = S[SWZ(h)];
        if (i >= 13) wsum -= S[SWZ(i - 13)];
        if (i < 12) wsum += (float)(12 - i) * x0;
        if (i > LROW - 13) wsum += (float)(i - (LROW - 13)) * xl;
        const float xi = r[k];
        const float rr = xi - wsum * 0.04f;
        s1 += rr; s2 += rr * rr;
        ob[k] = f2bf(xi);
    }

    uint4 o0, o1;
    o0.x = (u32)ob[0]  | ((u32)ob[1]  << 16);
    o0.y = (u32)ob[2]  | ((u32)ob[3]  << 16);
    o0.z = (u32)ob[4]  | ((u32)ob[5]  << 16);
    o0.w = (u32)ob[6]  | ((u32)ob[7]  << 16);
    o1.x = (u32)ob[8]  | ((u32)ob[9]  << 16);
    o1.y = (u32)ob[10] | ((u32)ob[11] << 16);
    o1.z = (u32)ob[12] | ((u32)ob[13] << 16);
    o1.w = (u32)ob[14] | ((u32)ob[15] << 16);
    uint4* op = (uint4*)(xbf + b * LROW + ((size_t)tid << 4));
    op[0] = o0; op[1] = o1;

    #pragma unroll
    for (int off = 32; off; off >>= 1) {
        s1 += __shfl_down(s1, off);
        s2 += __shfl_down(s2, off);
    }
    if (lane == 0) { rred[wv * 2] = s1; rred[wv * 2 + 1] = s2; }
    __syncthreads();
    if (tid == 0) {
        const float S1 = rred[0] + rred[2] + rred[4] + rred[6];
        const float S2 = rred[1] + rred[3] + rred[5] + rred[7];
        const float mean = S1 / (float)LROW;
        float var = (S2 - (float)LROW * mean * mean) / (float)(LROW - 1);
        var = var < 0.f ? 0.f : var;
        stdv[b] = sqrtf(var) + 1e-5f;
    }
}

// ---------------------------------------------------------------------------
// Kernel W: fold weights into G[p][l] (bf16), rows 720..767 zero-padded.
// ---------------------------------------------------------------------------
__global__ __launch_bounds__(256) void prep_weights(const float* __restrict__ Wt,
                                                    const float* __restrict__ Wlo,
                                                    const float* __restrict__ Whi,
                                                    u16* __restrict__ Gm) {
    __shared__ float S[LROW];
    __shared__ float wred[4];
    __shared__ float sred[4];
    const int tid = threadIdx.x;
    const int lane = tid & 63, wv = tid >> 6;
    const int p = blockIdx.x;
    u16* grow = Gm + (size_t)p * LROW;
    if (p >= PCOL) {
        uint4 z; z.x = z.y = z.z = z.w = 0u;
        uint4* g4 = (uint4*)grow;
        for (int i = tid; i < LROW / 8; i += 256) g4[i] = z;
        return;
    }
    const float4* wt4 = (const float4*)(Wt + (size_t)p * LROW);
    float4 q0 = wt4[tid * 4 + 0], q1 = wt4[tid * 4 + 1];
    float4 q2 = wt4[tid * 4 + 2], q3 = wt4[tid * 4 + 3];
    const float4* lo4 = (const float4*)(Wlo + (size_t)p * HH);
    const float4* hi4 = (const float4*)(Whi + (size_t)p * HH);
    float4 a0 = lo4[tid * 2 + 0], a1 = lo4[tid * 2 + 1];
    float4 b0 = hi4[tid * 2 + 0], b1 = hi4[tid * 2 + 1];

    float w[16];
    w[0]=q0.x; w[1]=q0.y; w[2]=q0.z; w[3]=q0.w;
    w[4]=q1.x; w[5]=q1.y; w[6]=q1.z; w[7]=q1.w;
    w[8]=q2.x; w[9]=q2.y; w[10]=q2.z; w[11]=q2.w;
    w[12]=q3.x; w[13]=q3.y; w[14]=q3.z; w[15]=q3.w;
    float lv[8] = {a0.x,a0.y,a0.z,a0.w,a1.x,a1.y,a1.z,a1.w};
    float hv[8] = {b0.x,b0.y,b0.z,b0.w,b1.x,b1.y,b1.z,b1.w};

    float u[16], z_[16];
    float slo = 0.f;
    #pragma unroll
    for (int j = 0; j < 8; ++j) {
        u[2*j]   = (lv[j] + hv[j]) * INV_SQRT2F;
        u[2*j+1] = (lv[j] - hv[j]) * INV_SQRT2F;
        slo += lv[j];
    }
    #pragma unroll
    for (int k = 0; k < 16; ++k) z_[k] = w[k] - u[k];

    float ps[16];
    float a = 0.f;
    #pragma unroll
    for (int k = 0; k < 16; ++k) { a += z_[k]; ps[k] = a; }
    const float segsum = a;

    float v = segsum;
    #pragma unroll
    for (int off = 1; off < 64; off <<= 1) {
        float o = __shfl_up(v, off);
        if (lane >= off) v += o;
    }
    if (lane == 63) wred[wv] = v;
    #pragma unroll
    for (int off = 32; off; off >>= 1) slo += __shfl_down(slo, off);
    if (lane == 0) sred[wv] = slo;
    __syncthreads();

    float wbase = 0.f;
    #pragma unroll
    for (int ww = 0; ww < 4; ++ww) if (ww < wv) wbase += wred[ww];
    const float ebase = wbase + v - segsum;
    const float SLO = sred[0] + sred[1] + sred[2] + sred[3];

    #pragma unroll
    for (int k = 0; k < 16; ++k) {
        const int i = (tid << 4) + k;
        S[SWZ(i)] = ebase + ps[k];
    }
    __syncthreads();

    const float coef = -1.4142135623730951f * SLO / (float)LROW;
    u16 ob[16];
    #pragma unroll
    for (int k = 0; k < 16; ++k) {
        const int l = (tid << 4) + k;
        float zT;
        if (l == 0) {
            float acc = 0.f;
            for (int m = 0; m <= 12; ++m) acc += S[SWZ(m)];
            zT = acc * 0.04f;
        } else if (l == LROW - 1) {
            float acc = 0.f;
            for (int m = 0; m <= 12; ++m) acc += S[SWZ(LROW - 2 - m)];
            zT = (13.f * S[SWZ(LROW - 1)] - acc) * 0.04f;
        } else {
            int h = l + 12; h = h > LROW - 1 ? LROW - 1 : h;
            float t_ = S[SWZ(h)];
            if (l >= 13) t_ -= S[SWZ(l - 13)];
            zT = t_ * 0.04f;
        }
        float c;
        const int dmin = l < (LROW - 1 - l) ? l : (LROW - 1 - l);
        if (dmin >= 12)      c = 0.f;
        else if (dmin == 0)  c = -66.f / 25.f;
        else                 c = (float)(12 - dmin) * 0.04f;
        ob[k] = f2bf(zT + u[k] + coef * c);
    }

    uint4 o0, o1;
    o0.x = (u32)ob[0]  | ((u32)ob[1]  << 16);
    o0.y = (u32)ob[2]  | ((u32)ob[3]  << 16);
    o0.z = (u32)ob[4]  | ((u32)ob[5]  << 16);
    o0.w = (u32)ob[6]  | ((u32)ob[7]  << 16);
    o1.x = (u32)ob[8]  | ((u32)ob[9]  << 16);
    o1.y = (u32)ob[10] | ((u32)ob[11] << 16);
    o1.z = (u32)ob[12] | ((u32)ob[13] << 16);
    o1.w = (u32)ob[14] | ((u32)ob[15] << 16);
    uint4* op = (uint4*)(grow + ((size_t)tid << 4));
    op[0] = o0; op[1] = o1;
}

// ---------------------------------------------------------------------------
// Kernel G: fused GEMM, BM=128 BN=96 BK=64, 256 thr = 4 waves (2wm x 2kp),
// wave tile 64x96. NEW (R10): quartered LDS layout, all frag reads contiguous
// 1KB (conflict-free, NO swizzle); A quarters SELF-STAGED per wave so A-frag
// prefetch (lead-1) runs after MFMA guarded only by own counted vmcnt.
// A 3-deep (DMA lead-2), B 2-deep (lead-1); NO vmcnt(0) in main loop:
//   vmcnt(4)[B(t) done] -> barrier -> stage B(t+1),A(t+2) -> read 6 B-frags
//   -> lgkm(0) -> 24 MFMA (A in regs) -> vmcnt(7)[A(t+1) done] -> read A(t+1).
// 72KB LDS -> 2 blocks/CU. kp-pair reduce + fused bias/std epilogue.
// ---------------------------------------------------------------------------
typedef __attribute__((address_space(1))) void gvoid;
typedef __attribute__((address_space(3))) void lvoid;
#define GLD16(g, l_) __builtin_amdgcn_global_load_lds((gvoid*)(g), (lvoid*)(l_), 16, 0, 0)
#define MF(a, b, c) __builtin_amdgcn_mfma_f32_16x16x32_bf16(a, b, c, 0, 0, 0)

#define ABUFB 16384           // [2wm][2kp][64 rows][64B]
#define BBASE 49152           // A: 3 x 16KB
#define BBUFB 12288           // [2kp][96 rows][64B]

// wave stages its own A quarter: 4 gld16, each 16 rows x 64B (1KB contiguous)
#define STAGE_A(T, DB) do { \
    char* d_ = Sm + (DB) * ABUFB + aqb; \
    const size_t go_ = (size_t)(T) * 128; \
    GLD16(sA + go_,          d_); \
    GLD16(sA + go_ + 131072, d_ + 1024); \
    GLD16(sA + go_ + 262144, d_ + 2048); \
    GLD16(sA + go_ + 393216, d_ + 3072); \
} while (0)

// wave stages B rows [wm*48,+48) of half kp: 3 gld16
#define STAGE_B(T, DB) do { \
    char* d_ = Sm + BBASE + (DB) * BBUFB + bqb; \
    const size_t go_ = (size_t)(T) * 128; \
    GLD16(sB + go_,          d_); \
    GLD16(sB + go_ + 131072, d_ + 1024); \
    GLD16(sB + go_ + 262144, d_ + 2048); \
} while (0)

#define READ_B(DB) do { \
    const char* b_ = Sm + BBASE + (DB) * BBUFB + bro; \
    B0 = *(const bf16x8*)(b_); \
    B1 = *(const bf16x8*)(b_ + 1024); \
    B2 = *(const bf16x8*)(b_ + 2048); \
    B3 = *(const bf16x8*)(b_ + 3072); \
    B4 = *(const bf16x8*)(b_ + 4096); \
    B5 = *(const bf16x8*)(b_ + 5120); \
} while (0)

#define READ_A(P, DB) do { \
    const char* a_ = Sm + (DB) * ABUFB + aro; \
    P##0 = *(const bf16x8*)(a_); \
    P##1 = *(const bf16x8*)(a_ + 1024); \
    P##2 = *(const bf16x8*)(a_ + 2048); \
    P##3 = *(const bf16x8*)(a_ + 3072); \
} while (0)

// n-outer so the first MFMAs need only B0
#define MFMA24(P) do { \
    acc[0][0]=MF(P##0,B0,acc[0][0]); acc[1][0]=MF(P##1,B0,acc[1][0]); \
    acc[2][0]=MF(P##2,B0,acc[2][0]); acc[3][0]=MF(P##3,B0,acc[3][0]); \
    acc[0][1]=MF(P##0,B1,acc[0][1]); acc[1][1]=MF(P##1,B1,acc[1][1]); \
    acc[2][1]=MF(P##2,B1,acc[2][1]); acc[3][1]=MF(P##3,B1,acc[3][1]); \
    acc[0][2]=MF(P##0,B2,acc[0][2]); acc[1][2]=MF(P##1,B2,acc[1][2]); \
    acc[2][2]=MF(P##2,B2,acc[2][2]); acc[3][2]=MF(P##3,B2,acc[3][2]); \
    acc[0][3]=MF(P##0,B3,acc[0][3]); acc[1][3]=MF(P##1,B3,acc[1][3]); \
    acc[2][3]=MF(P##2,B3,acc[2][3]); acc[3][3]=MF(P##3,B3,acc[3][3]); \
    acc[0][4]=MF(P##0,B4,acc[0][4]); acc[1][4]=MF(P##1,B4,acc[1][4]); \
    acc[2][4]=MF(P##2,B4,acc[2][4]); acc[3][4]=MF(P##3,B4,acc[3][4]); \
    acc[0][5]=MF(P##0,B5,acc[0][5]); acc[1][5]=MF(P##1,B5,acc[1][5]); \
    acc[2][5]=MF(P##2,B5,acc[2][5]); acc[3][5]=MF(P##3,B5,acc[3][5]); \
} while (0)

#define ITER(T, CUR, NXT, ARD, AST, BRD, BST, V1, V2, SB, SA, RDA) do { \
    asm volatile("s_waitcnt vmcnt(" #V1 ")" ::: "memory"); \
    __builtin_amdgcn_s_barrier(); \
    __builtin_amdgcn_sched_barrier(0); \
    if (SB) STAGE_B((T) + 1, BST); \
    if (SA) STAGE_A((T) + 2, AST); \
    __builtin_amdgcn_sched_barrier(0); \
    READ_B(BRD); \
    asm volatile("s_waitcnt lgkmcnt(0)" ::: "memory"); \
    __builtin_amdgcn_sched_barrier(0); \
    __builtin_amdgcn_s_setprio(1); \
    MFMA24(CUR); \
    __builtin_amdgcn_s_setprio(0); \
    __builtin_amdgcn_sched_barrier(0); \
    if (RDA) { \
        asm volatile("s_waitcnt vmcnt(" #V2 ")" ::: "memory"); \
        __builtin_amdgcn_sched_barrier(0); \
        READ_A(NXT, ARD); \
    } \
} while (0)

__global__ __launch_bounds__(256, 2) void gemm_fused(const u16* __restrict__ Abf,
                                                     const u16* __restrict__ Gbf,
                                                     const float* __restrict__ bt,
                                                     const float* __restrict__ bl,
                                                     const float* __restrict__ bh,
                                                     const float* __restrict__ stdv,
                                                     float* __restrict__ out) {
    __shared__ __align__(16) char Sm[73728];   // A 3x16KB | B 2x12KB
    const int tid = threadIdx.x;
    const int l = tid & 63, wid = tid >> 6;    // wid 0..3
    const int wm = wid & 1, kp = wid >> 1;

    // XCD-chunked swizzle: 512 = 8 XCDs x 64; n fastest within chunk
    const int orig = blockIdx.x;
    const int chunk = orig & 7, pos = orig >> 3;
    const int bx = pos & 7;
    const int by = (chunk << 3) + (pos >> 3);
    const int m0 = by * 128;
    const int n0 = bx * 96;

    // ---- staging source pointers (per-lane): row +(l>>2), k-byte (l&3)*16
    const char* sA = (const char*)Abf
        + ((size_t)(m0 + wm * 64 + (l >> 2)) << 13) + kp * 64 + ((l & 3) << 4);
    const char* sB = (const char*)Gbf
        + ((size_t)(n0 + wm * 48 + (l >> 2)) << 13) + kp * 64 + ((l & 3) << 4);
    // wave-uniform LDS bases
    const int aqb = wm * 8192 + kp * 4096;     // own A quarter
    const int bqb = kp * 6144 + wm * 3072;     // B half-kp, wm sub-block

    // ---- frag read offsets: contiguous 1KB per frag ----
    const int aro = wm * 8192 + kp * 4096 + ((l & 15) << 6) + ((l >> 4) << 4);
    const int bro = kp * 6144 + ((l & 15) << 6) + ((l >> 4) << 4);

    f32x4 acc[4][6] = {};
    bf16x8 X0, X1, X2, X3, Y0, Y1, Y2, Y3;
    bf16x8 B0, B1, B2, B3, B4, B5;

    // ---- prologue: A(0)->a0 [4], B(0)->b0 [3], A(1)->a1 [4]; retire A0+B0 ----
    STAGE_A(0, 0);
    STAGE_B(0, 0);
    STAGE_A(1, 1);
    asm volatile("s_waitcnt vmcnt(4)" ::: "memory");
    __builtin_amdgcn_s_barrier();
    __builtin_amdgcn_sched_barrier(0);
    READ_A(X, 0);

    //      T   CUR NXT ARD AST BRD BST V1 V2 SB SA RDA
    for (int t = 0; t < 60; t += 6) {
        ITER(t + 0, X, Y, 1, 2, 0, 1, 4, 7, 1, 1, 1);
        ITER(t + 1, Y, X, 2, 0, 1, 0, 4, 7, 1, 1, 1);
        ITER(t + 2, X, Y, 0, 1, 0, 1, 4, 7, 1, 1, 1);
        ITER(t + 3, Y, X, 1, 2, 1, 0, 4, 7, 1, 1, 1);
        ITER(t + 4, X, Y, 2, 0, 0, 1, 4, 7, 1, 1, 1);
        ITER(t + 5, Y, X, 0, 1, 1, 0, 4, 7, 1, 1, 1);
    }
    ITER(60, X, Y, 1, 2, 0, 1, 4, 7, 1, 1, 1);   // stages B61, A62
    ITER(61, Y, X, 2, 0, 1, 0, 4, 7, 1, 1, 1);   // stages B62, A63
    ITER(62, X, Y, 0, 0, 0, 1, 4, 3, 1, 0, 1);   // stages B63 only
    ITER(63, Y, X, 0, 0, 1, 0, 0, 0, 0, 0, 0);

    // ---- kp-pair reduce (kp1 -> LDS, kp0 adds) + fused bias epilogue ----
    __syncthreads();
    float* red = (float*)Sm;
    const int rr = (l >> 4) << 2;
    const int cc = l & 15;
    const int rbase = wm * 6528;              // 96 cols x 68 floats
    if (kp == 1) {
        #pragma unroll
        for (int m = 0; m < 4; ++m)
            #pragma unroll
            for (int n = 0; n < 6; ++n)
                *(f32x4*)(red + rbase + (n * 16 + cc) * 68 + m * 16 + rr) = acc[m][n];
    }
    __syncthreads();
    if (kp == 0) {
        const int crow = m0 + wm * 64 + rr;
        const int ccol = n0 + cc;
        float btv[6], bsv[6];
        #pragma unroll
        for (int n = 0; n < 6; ++n) {
            const int col = ccol + n * 16;
            if (col < PCOL) { btv[n] = bt[col]; bsv[n] = bl[col] + bh[col]; }
            else            { btv[n] = 0.f; bsv[n] = 0.f; }
        }
        #pragma unroll
        for (int m = 0; m < 4; ++m) {
            const int row = crow + m * 16;
            const float4 sv = *(const float4*)(stdv + row);
            #pragma unroll
            for (int n = 0; n < 6; ++n) {
                const int col = ccol + n * 16;
                if (col < PCOL) {
                    const f32x4 pv = *(const f32x4*)(red + rbase + (n * 16 + cc) * 68 + m * 16 + rr);
                    float* orow = out + (size_t)row * PCOL + col;
                    #pragma unroll
                    for (int j = 0; j < 4; ++j) {
                        const float s = (j == 0) ? sv.x : (j == 1) ? sv.y : (j == 2) ? sv.z : sv.w;
                        orow[(size_t)j * PCOL] = acc[m][n][j] + pv[j] + btv[n] + s * bsv[n];
                    }
                }
            }
        }
    }
}

// ---------------------------------------------------------------------------
extern "C" void kernel_launch(void* const* d_in, const int* in_sizes, int n_in,
                              void* d_out, int out_size, void* d_ws, size_t ws_size,
                              hipStream_t stream) {
    (void)in_sizes; (void)n_in; (void)out_size;
    if (ws_size < WS_MIN) return;

    const float* x  = (const float*)d_in[0];
    const float* Wt = (const float*)d_in[1];
    const float* bt = (const float*)d_in[2];
    const float* Wl = (const float*)d_in[3];
    const float* bl = (const float*)d_in[4];
    const float* Wh = (const float*)d_in[5];
    const float* bh = (const float*)d_in[6];
    float* out = (float*)d_out;

    char* ws = (char*)d_ws;
    u16*   xbf = (u16*)ws;
    u16*   Gm  = (u16*)(ws + WS_XBF_BYTES);
    float* sd  = (float*)(ws + WS_XBF_BYTES + WS_G_BYTES);

    prep_rows<<<NB, 256, 0, stream>>>(x, xbf, sd);
    prep_weights<<<NPAD, 256, 0, stream>>>(Wt, Wl, Wh, Gm);
    gemm_fused<<<512, 256, 0, stream>>>(xbf, Gm, bt, bl, bh, sd, out);
}